// Round 6
// baseline (591.137 us; speedup 1.0000x reference)
//
#include <hip/hip_runtime.h>

// ---- static configuration (mirrors reference) ----
#define N_SHOTS 8
#define NZP 304
#define NXP 304
#define NT 50
#define N_REC 300
#define FLAT (NZP * NXP)          // 92416
#define DT 0.001f
#define INV_DX 0.25f              // 1/4.0
#define INV_DX2 0.0625f           // 1/16.0

#define C23 (2.0f / 3.0f)
#define C112 (1.0f / 12.0f)
#define C43 (4.0f / 3.0f)

// One FDTD time step, fully fused:
//  - threads 0..303: stencil update for one row (z fixed per block)
//  - threads 304..319 of blocks 0..149: receiver gather from pre-step wfc
//  - source injection folded into the cell update
// Buffering: wfc_new overwrites wfp in place (same-cell read only);
// psi double-buffered (neighbors read); zeta in place (same-cell only).
__global__ __launch_bounds__(320) void fdtd_step(
    const float* __restrict__ v,
    const float* __restrict__ amp,        // (NT, N_SHOTS, 1)
    const float* __restrict__ az, const float* __restrict__ bz, const float* __restrict__ dbz,
    const float* __restrict__ ax, const float* __restrict__ bx, const float* __restrict__ dbx,
    const int* __restrict__ src_i,        // (N_SHOTS, 1)
    const int* __restrict__ rec_i,        // (N_SHOTS, N_REC)
    const float* __restrict__ wfc,        // current wavefield (read-only this step)
    float* __restrict__ wfp,              // previous wavefield; overwritten with wfc_new
    const float* __restrict__ pzin, float* __restrict__ pzout,
    const float* __restrict__ pxin, float* __restrict__ pxout,
    float* __restrict__ zzeta, float* __restrict__ xzeta,   // updated in place
    float* __restrict__ rec_out,          // (NT, N_SHOTS, N_REC)
    int t)
{
    const int bid = blockIdx.x;
    const int shot = bid / NZP;
    const int z = bid - shot * NZP;
    const int tid = threadIdx.x;

    if (tid >= NXP) {
        // receiver gather (reads pre-step wfc; no ordering hazard)
        int gidx = bid * 16 + (tid - NXP);
        if (gidx < N_SHOTS * N_REC) {
            int rshot = gidx / N_REC;
            rec_out[t * (N_SHOTS * N_REC) + gidx] =
                wfc[rshot * FLAT + rec_i[gidx]];
        }
        return;
    }

    const int x = tid;
    const int idx = shot * FLAT + z * NXP + x;

    // ---- loads (zero-extended outside the padded grid, matching jnp.pad) ----
    const float c = wfc[idx];

    float xm1 = 0.f, xm2 = 0.f, xp1 = 0.f, xp2 = 0.f;
    float apxm1 = 0.f, apxm2 = 0.f, apxp1 = 0.f, apxp2 = 0.f;
    if (x >= 1)       { xm1 = wfc[idx - 1]; apxm1 = ax[x - 1] * pxin[idx - 1]; }
    if (x >= 2)       { xm2 = wfc[idx - 2]; apxm2 = ax[x - 2] * pxin[idx - 2]; }
    if (x < NXP - 1)  { xp1 = wfc[idx + 1]; apxp1 = ax[x + 1] * pxin[idx + 1]; }
    if (x < NXP - 2)  { xp2 = wfc[idx + 2]; apxp2 = ax[x + 2] * pxin[idx + 2]; }

    float zm1 = 0.f, zm2 = 0.f, zp1 = 0.f, zp2 = 0.f;
    float apzm1 = 0.f, apzm2 = 0.f, apzp1 = 0.f, apzp2 = 0.f;
    if (z >= 1)       { zm1 = wfc[idx - NXP];     apzm1 = az[z - 1] * pzin[idx - NXP]; }
    if (z >= 2)       { zm2 = wfc[idx - 2 * NXP]; apzm2 = az[z - 2] * pzin[idx - 2 * NXP]; }
    if (z < NZP - 1)  { zp1 = wfc[idx + NXP];     apzp1 = az[z + 1] * pzin[idx + NXP]; }
    if (z < NZP - 2)  { zp2 = wfc[idx + 2 * NXP]; apzp2 = az[z + 2] * pzin[idx + 2 * NXP]; }

    // ---- z-dimension (axis 1) ----
    const float az_ = az[z], bz_ = bz[z], dbz_ = dbz[z];
    const float d1z = ((zp1 - zm1) * C23 + (zm2 - zp2) * C112) * INV_DX;
    const float d2z = (-2.5f * c + C43 * (zp1 + zm1) - C112 * (zp2 + zm2)) * INV_DX2;
    const float dapz = ((apzp1 - apzm1) * C23 + (apzm2 - apzp2) * C112) * INV_DX;
    const float tmpz = (1.f + bz_) * d2z + dbz_ * d1z + dapz;
    const float zz_c = zzeta[idx];
    const float pz_c = pzin[idx];
    float w_sum = (1.f + bz_) * tmpz + az_ * zz_c;

    // ---- x-dimension (axis 2) ----
    const float ax_ = ax[x], bx_ = bx[x], dbx_ = dbx[x];
    const float d1x = ((xp1 - xm1) * C23 + (xm2 - xp2) * C112) * INV_DX;
    const float d2x = (-2.5f * c + C43 * (xp1 + xm1) - C112 * (xp2 + xm2)) * INV_DX2;
    const float dapx = ((apxp1 - apxm1) * C23 + (apxm2 - apxp2) * C112) * INV_DX;
    const float tmpx = (1.f + bx_) * d2x + dbx_ * d1x + dapx;
    const float zx_c = xzeta[idx];
    const float px_c = pxin[idx];
    w_sum += (1.f + bx_) * tmpx + ax_ * zx_c;

    // ---- time update ----
    const float vv = v[z * NXP + x];
    float wn = (vv * vv) * (DT * DT) * w_sum + 2.f * c - wfp[idx];

    // source injection (N_SRC == 1)
    if (z * NXP + x == src_i[shot])
        wn += amp[t * N_SHOTS + shot];

    wfp[idx]   = wn;                       // becomes wfc for next step
    pzout[idx] = bz_ * d1z + az_ * pz_c;
    pxout[idx] = bx_ * d1x + ax_ * px_c;
    zzeta[idx] = bz_ * tmpz + az_ * zz_c;
    xzeta[idx] = bx_ * tmpx + ax_ * zx_c;
}

extern "C" void kernel_launch(void* const* d_in, const int* in_sizes, int n_in,
                              void* d_out, int out_size, void* d_ws, size_t ws_size,
                              hipStream_t stream) {
    const float* v     = (const float*)d_in[0];
    const float* amp   = (const float*)d_in[1];
    const float* az    = (const float*)d_in[2];
    const float* bz    = (const float*)d_in[3];
    const float* dbz   = (const float*)d_in[4];
    const float* ax    = (const float*)d_in[5];
    const float* bx    = (const float*)d_in[6];
    const float* dbx   = (const float*)d_in[7];
    const int* src_i   = (const int*)d_in[8];
    const int* rec_i   = (const int*)d_in[9];
    float* out = (float*)d_out;

    float* ws = (float*)d_ws;
    const size_t A = (size_t)N_SHOTS * FLAT;

    // state layout in workspace (8 arrays): wf0, wf1, pz0, pz1, px0, px1, zz, zx
    float* wf[2] = { ws + 0 * A, ws + 1 * A };
    float* pz[2] = { ws + 2 * A, ws + 3 * A };
    float* px[2] = { ws + 4 * A, ws + 5 * A };
    float* zz    = ws + 6 * A;
    float* zx    = ws + 7 * A;

    // zero all state (harness re-poisons ws to 0xAA before every call)
    hipMemsetAsync(d_ws, 0, 8 * A * sizeof(float), stream);

    int cur = 0;
    for (int t = 0; t < NT; ++t) {
        fdtd_step<<<N_SHOTS * NZP, 320, 0, stream>>>(
            v, amp, az, bz, dbz, ax, bx, dbx, src_i, rec_i,
            wf[cur], wf[1 - cur],
            pz[cur], pz[1 - cur],
            px[cur], px[1 - cur],
            zz, zx, out, t);
        cur ^= 1;
    }
}

// Round 7
// 453.691 us; speedup vs baseline: 1.3030x; 1.3030x over previous
//
#include <hip/hip_runtime.h>

// ---- static configuration (mirrors reference) ----
#define N_SHOTS 8
#define NZP 304
#define NXP 304
#define NT 50
#define N_REC 300
#define FLAT (NZP * NXP)          // 92416
#define DT 0.001f
#define INV_DX 0.25f              // 1/4.0
#define INV_DX2 0.0625f           // 1/16.0

#define C23 (2.0f / 3.0f)
#define C112 (1.0f / 12.0f)
#define C43 (4.0f / 3.0f)

// One FDTD time step, fully fused:
//  - threads 0..303: stencil update for one row (z fixed per block)
//  - threads 304..319 of the first 150 hardware blocks: receiver gather
//  - source injection folded into the cell update
// XCD swizzle: hardware assigns workgroups round-robin to the 8 XCDs by
// dispatch id, so shot = bid&7 pins each shot's 304 rows (2.9 MB state)
// to ONE XCD's 4 MB L2 -> z-neighbor reads are same-die L2 hits.
__global__ __launch_bounds__(320) void fdtd_step(
    const float* __restrict__ v,
    const float* __restrict__ amp,        // (NT, N_SHOTS, 1)
    const float* __restrict__ az, const float* __restrict__ bz, const float* __restrict__ dbz,
    const float* __restrict__ ax, const float* __restrict__ bx, const float* __restrict__ dbx,
    const int* __restrict__ src_i,        // (N_SHOTS, 1)
    const int* __restrict__ rec_i,        // (N_SHOTS, N_REC)
    const float* __restrict__ wfc,        // current wavefield (read-only this step)
    float* __restrict__ wfp,              // previous wavefield; overwritten with wfc_new
    const float* __restrict__ pzin, float* __restrict__ pzout,
    const float* __restrict__ pxin, float* __restrict__ pxout,
    float* __restrict__ zzeta, float* __restrict__ xzeta,   // updated in place
    float* __restrict__ rec_out,          // (NT, N_SHOTS, N_REC)
    int t)
{
    const int bid = blockIdx.x;
    // XCD-aware swizzle: shot s -> XCD s (8 XCDs, round-robin by dispatch id)
    const int shot = bid & 7;
    const int z = bid >> 3;
    const int tid = threadIdx.x;

    if (tid >= NXP) {
        // receiver gather (reads pre-step wfc; no ordering hazard)
        int gidx = bid * 16 + (tid - NXP);
        if (gidx < N_SHOTS * N_REC) {
            int rshot = gidx / N_REC;
            rec_out[t * (N_SHOTS * N_REC) + gidx] =
                wfc[rshot * FLAT + rec_i[gidx]];
        }
        return;
    }

    const int x = tid;
    const int idx = shot * FLAT + z * NXP + x;

    // ---- loads (zero-extended outside the padded grid, matching jnp.pad) ----
    const float c = wfc[idx];

    float xm1 = 0.f, xm2 = 0.f, xp1 = 0.f, xp2 = 0.f;
    float apxm1 = 0.f, apxm2 = 0.f, apxp1 = 0.f, apxp2 = 0.f;
    if (x >= 1)       { xm1 = wfc[idx - 1]; apxm1 = ax[x - 1] * pxin[idx - 1]; }
    if (x >= 2)       { xm2 = wfc[idx - 2]; apxm2 = ax[x - 2] * pxin[idx - 2]; }
    if (x < NXP - 1)  { xp1 = wfc[idx + 1]; apxp1 = ax[x + 1] * pxin[idx + 1]; }
    if (x < NXP - 2)  { xp2 = wfc[idx + 2]; apxp2 = ax[x + 2] * pxin[idx + 2]; }

    float zm1 = 0.f, zm2 = 0.f, zp1 = 0.f, zp2 = 0.f;
    float apzm1 = 0.f, apzm2 = 0.f, apzp1 = 0.f, apzp2 = 0.f;
    if (z >= 1)       { zm1 = wfc[idx - NXP];     apzm1 = az[z - 1] * pzin[idx - NXP]; }
    if (z >= 2)       { zm2 = wfc[idx - 2 * NXP]; apzm2 = az[z - 2] * pzin[idx - 2 * NXP]; }
    if (z < NZP - 1)  { zp1 = wfc[idx + NXP];     apzp1 = az[z + 1] * pzin[idx + NXP]; }
    if (z < NZP - 2)  { zp2 = wfc[idx + 2 * NXP]; apzp2 = az[z + 2] * pzin[idx + 2 * NXP]; }

    // ---- z-dimension (axis 1) ----
    const float az_ = az[z], bz_ = bz[z], dbz_ = dbz[z];
    const float d1z = ((zp1 - zm1) * C23 + (zm2 - zp2) * C112) * INV_DX;
    const float d2z = (-2.5f * c + C43 * (zp1 + zm1) - C112 * (zp2 + zm2)) * INV_DX2;
    const float dapz = ((apzp1 - apzm1) * C23 + (apzm2 - apzp2) * C112) * INV_DX;
    const float tmpz = (1.f + bz_) * d2z + dbz_ * d1z + dapz;
    const float zz_c = zzeta[idx];
    const float pz_c = pzin[idx];
    float w_sum = (1.f + bz_) * tmpz + az_ * zz_c;

    // ---- x-dimension (axis 2) ----
    const float ax_ = ax[x], bx_ = bx[x], dbx_ = dbx[x];
    const float d1x = ((xp1 - xm1) * C23 + (xm2 - xp2) * C112) * INV_DX;
    const float d2x = (-2.5f * c + C43 * (xp1 + xm1) - C112 * (xp2 + xm2)) * INV_DX2;
    const float dapx = ((apxp1 - apxm1) * C23 + (apxm2 - apxp2) * C112) * INV_DX;
    const float tmpx = (1.f + bx_) * d2x + dbx_ * d1x + dapx;
    const float zx_c = xzeta[idx];
    const float px_c = pxin[idx];
    w_sum += (1.f + bx_) * tmpx + ax_ * zx_c;

    // ---- time update ----
    const float vv = v[z * NXP + x];
    float wn = (vv * vv) * (DT * DT) * w_sum + 2.f * c - wfp[idx];

    // source injection (N_SRC == 1)
    if (z * NXP + x == src_i[shot])
        wn += amp[t * N_SHOTS + shot];

    wfp[idx]   = wn;                       // becomes wfc for next step
    pzout[idx] = bz_ * d1z + az_ * pz_c;
    pxout[idx] = bx_ * d1x + ax_ * px_c;
    zzeta[idx] = bz_ * tmpz + az_ * zz_c;
    xzeta[idx] = bx_ * tmpx + ax_ * zx_c;
}

extern "C" void kernel_launch(void* const* d_in, const int* in_sizes, int n_in,
                              void* d_out, int out_size, void* d_ws, size_t ws_size,
                              hipStream_t stream) {
    const float* v     = (const float*)d_in[0];
    const float* amp   = (const float*)d_in[1];
    const float* az    = (const float*)d_in[2];
    const float* bz    = (const float*)d_in[3];
    const float* dbz   = (const float*)d_in[4];
    const float* ax    = (const float*)d_in[5];
    const float* bx    = (const float*)d_in[6];
    const float* dbx   = (const float*)d_in[7];
    const int* src_i   = (const int*)d_in[8];
    const int* rec_i   = (const int*)d_in[9];
    float* out = (float*)d_out;

    float* ws = (float*)d_ws;
    const size_t A = (size_t)N_SHOTS * FLAT;

    // state layout in workspace (8 arrays): wf0, wf1, pz0, pz1, px0, px1, zz, zx
    float* wf[2] = { ws + 0 * A, ws + 1 * A };
    float* pz[2] = { ws + 2 * A, ws + 3 * A };
    float* px[2] = { ws + 4 * A, ws + 5 * A };
    float* zz    = ws + 6 * A;
    float* zx    = ws + 7 * A;

    // zero all state (harness re-poisons ws to 0xAA before every call)
    hipMemsetAsync(d_ws, 0, 8 * A * sizeof(float), stream);

    int cur = 0;
    for (int t = 0; t < NT; ++t) {
        fdtd_step<<<N_SHOTS * NZP, 320, 0, stream>>>(
            v, amp, az, bz, dbz, ax, bx, dbx, src_i, rec_i,
            wf[cur], wf[1 - cur],
            pz[cur], pz[1 - cur],
            px[cur], px[1 - cur],
            zz, zx, out, t);
        cur ^= 1;
    }
}